// Round 1
// baseline (422.175 us; speedup 1.0000x reference)
//
#include <hip/hip_runtime.h>
#include <hip/hip_bf16.h>
#include <math.h>

typedef __hip_bfloat16 bf;

#define BB   16     // batch
#define CC   128    // channels
#define LL   4096   // H*W
#define DM   32     // d_model per chunk
#define DI   64     // d_inner
#define DSN  16     // d_state
#define GG   64     // 4 * BB sequences
#define NC   64     // scan chunks
#define CL   64     // LL / NC
#define TLV  61     // valid output columns per k1 tile (64 loaded, 3 head)
#define NT   68     // ceil(LL / TLV)
#define XS   133    // k1 xnT row stride in dwords (odd -> conflict-free)
#define YS   35     // k1 xiS row stride in dwords
#define XROW 20     // xdbl row stride in dwords (80 B: dw0=dt01, dw1-3 pad, dw4-11=B, dw12-19=C)

__device__ __forceinline__ float bf2f(bf x) { return __bfloat162float(x); }
__device__ __forceinline__ bf f2bf(float x) { return __float2bfloat16(x); }
__device__ __forceinline__ float blo(unsigned v) { return __uint_as_float(v << 16); }
__device__ __forceinline__ float bhi(unsigned v) { return __uint_as_float(v & 0xffff0000u); }
__device__ __forceinline__ float us2f(unsigned short v) { return __uint_as_float((unsigned)v << 16); }
__device__ __forceinline__ unsigned pack2(float a, float b) {
  bf ba = f2bf(a), bb = f2bf(b);
  unsigned short ua = *(unsigned short*)&ba, ub = *(unsigned short*)&bb;
  return (unsigned)ua | ((unsigned)ub << 16);
}

#if __has_builtin(__builtin_amdgcn_exp2f)
#define EXP2F(x) __builtin_amdgcn_exp2f(x)
#else
#define EXP2F(x) exp2f(x)
#endif

// wave-uniform broadcast from lane l: result lands in SGPRs -> SALU unpack co-issues
#if __has_builtin(__builtin_amdgcn_readlane)
#define RL(v, l) ((unsigned)__builtin_amdgcn_readlane((int)(v), (l)))
#else
#define RL(v, l) ((unsigned)__shfl((int)(v), (l), 64))
#endif

__device__ __forceinline__ float sigmoidf_(float x) { return 1.0f / (1.0f + __expf(-x)); }
// fast softplus: max(x,0) + ln2 * log2(1 + exp2(-|x|*log2e))
__device__ __forceinline__ float softplus_fast(float x) {
  float t = EXP2F(-fabsf(x) * 1.44269504088896f);
  return fmaxf(x, 0.0f) + 0.69314718056f * __log2f(1.0f + t);
}
__device__ __forceinline__ void unpack8(uint4 v, float* o) {
  o[0] = blo(v.x); o[1] = bhi(v.x); o[2] = blo(v.y); o[3] = bhi(v.y);
  o[4] = blo(v.z); o[5] = bhi(v.z); o[6] = blo(v.w); o[7] = bhi(v.w);
}

// ---------------- K1: layernorm + in_proj(xi) + causal conv + silu -> u (bf16), xn (bf16) ----------------
// (unchanged)
__global__ __launch_bounds__(256, 4) void k1_ln_conv(
    const float* __restrict__ input, const float* __restrict__ ln_g, const float* __restrict__ ln_b,
    const float* __restrict__ in_proj_w, const float* __restrict__ conv_w, const float* __restrict__ conv_b,
    bf* __restrict__ u_ws, bf* __restrict__ xn_ws) {
  __shared__ unsigned ldsbuf[8960];               // union: xnT fp32 64x133dw / xiS bf16 256x35dw
  __shared__ float mu_s[64], rs_s[64];
  float* xnT = (float*)ldsbuf;
  unsigned short* xiS = (unsigned short*)ldsbuf;
  int b = blockIdx.x / NT;
  int tile = blockIdx.x - b * NT;
  int l0 = tile * TLV;
  int tid = threadIdx.x;
  const float* inb = input + (size_t)b * CC * LL;
#pragma unroll
  for (int k = 0; k < 32; k++) {
    int i = tid + k * 256;
    int j = i & 63, c = i >> 6;
    int l = l0 - 3 + j;
    xnT[j * XS + c] = (l >= 0 && l < LL) ? inb[c * LL + l] : 0.0f;
  }
  __syncthreads();
  if (tid < 64) {
    float s = 0.f, s2 = 0.f;
    for (int c = 0; c < CC; c++) { float v = xnT[tid * XS + c]; s += v; s2 = fmaf(v, v, s2); }
    float mu = s * (1.0f / CC);
    float var = s2 * (1.0f / CC) - mu * mu;
    mu_s[tid] = mu;
    rs_s[tid] = rsqrtf(var + 1e-5f);
  }
  __syncthreads();
#pragma unroll
  for (int k = 0; k < 32; k++) {
    int i = tid + k * 256;
    int j = i & 63, c = i >> 6;
    xnT[j * XS + c] = (xnT[j * XS + c] - mu_s[j]) * rs_s[j] * ln_g[c] + ln_b[c];
  }
  __syncthreads();
  for (int i = tid; i < CC * TLV; i += 256) {
    int c = i / TLV, j2 = i - c * TLV;
    int l = l0 + j2;
    if (l < LL) xn_ws[((size_t)(b * CC + c)) * LL + l] = f2bf(xnT[(j2 + 3) * XS + c]);
  }
  int g = tid >> 6, j = tid & 63;
  float xr[32];
#pragma unroll
  for (int r = 0; r < 32; r++) xr[r] = xnT[j * XS + g * DM + r];
  bool zero_col = (l0 - 3 + j < 0);
  __syncthreads();
#pragma unroll
  for (int c2 = 0; c2 < 4; c2++) {
    float acc[16];
#pragma unroll
    for (int dd = 0; dd < 16; dd++) {
      const float* w = in_proj_w + (c2 * 16 + dd) * DM;
      float a = 0.f;
#pragma unroll
      for (int r = 0; r < 32; r++) a = fmaf(xr[r], w[r], a);
      acc[dd] = zero_col ? 0.f : a;
    }
    unsigned* xo = (unsigned*)&ldsbuf[(g * 64 + j) * YS + c2 * 8];
#pragma unroll
    for (int k = 0; k < 8; k++)
      xo[k] = pack2(acc[2 * k], acc[2 * k + 1]);
  }
  __syncthreads();
  int d = j;
  float cw0 = conv_w[d * 4 + 0], cw1 = conv_w[d * 4 + 1];
  float cw2 = conv_w[d * 4 + 2], cw3 = conv_w[d * 4 + 3];
  float cb = conv_b[d];
  bf* uo = u_ws + (size_t)(g * BB + b) * LL * DI + d;
  float x3 = 0.f, x2 = 0.f, x1 = 0.f, x0 = 0.f;
  for (int jj = 0; jj < 64; jj++) {
    float xi = us2f(xiS[(g * 64 + jj) * (2 * YS) + d]);
    x3 = x2; x2 = x1; x1 = x0; x0 = xi;
    int l = l0 + jj - 3;
    if (jj >= 3 && l < LL) {
      float pre = x3 * cw0 + x2 * cw1 + x1 * cw2 + x0 * cw3 + cb;
      float uu = pre * sigmoidf_(pre);
      uo[(size_t)l * DI] = f2bf(uu);
    }
  }
}

// ---------------- K2: x_proj only -> xdbl rows (dt0,dt1,B,C packed bf16, 80 B/pos) ----------------
// (unchanged)
__global__ __launch_bounds__(256) void k2_xproj(
    const bf* __restrict__ u_ws, const float* __restrict__ x_proj_w,
    unsigned* __restrict__ xdbl) {
  __shared__ unsigned uS[256 * 33];
  int tid = threadIdx.x;
  size_t pos0 = (size_t)blockIdx.x * 256;
  const unsigned* src = (const unsigned*)u_ws + pos0 * 32;
#pragma unroll
  for (int k = 0; k < 32; k++) {
    int idx = tid + k * 256;
    uS[(idx >> 5) * 33 + (idx & 31)] = src[idx];
  }
  __syncthreads();
  float xdb[34];
#pragma unroll
  for (int e = 0; e < 34; e++) xdb[e] = 0.f;
#pragma unroll
  for (int c2 = 0; c2 < 4; c2++) {
    float f[16];
#pragma unroll
    for (int k = 0; k < 8; k++) {
      unsigned v = uS[tid * 33 + c2 * 8 + k];
      f[2 * k] = blo(v); f[2 * k + 1] = bhi(v);
    }
#pragma unroll
    for (int e = 0; e < 34; e++) {
      const float* w = x_proj_w + e * DI + c2 * 16;
      float a = xdb[e];
#pragma unroll
      for (int i = 0; i < 16; i++) a = fmaf(f[i], w[i], a);
      xdb[e] = a;
    }
  }
  unsigned* row = &uS[tid * 33];
  row[0] = pack2(xdb[0], xdb[1]);
#pragma unroll
  for (int n = 0; n < 8; n++) row[4 + n]  = pack2(xdb[2 + 2 * n], xdb[3 + 2 * n]);
#pragma unroll
  for (int n = 0; n < 8; n++) row[12 + n] = pack2(xdb[18 + 2 * n], xdb[19 + 2 * n]);
  __syncthreads();
  unsigned* dst = xdbl + pos0 * XROW;
#pragma unroll
  for (int k = 0; k < XROW; k++) {
    int idx = tid + k * 256;
    int r = idx / XROW, c = idx - r * XROW;
    dst[idx] = uS[r * 33 + c];
  }
}

// ---------------- K3: scan pass A — local states + chunk delta-sums ----------------
// NEW: per-lane row preload of xdbl (lane t holds row t) + v_readlane broadcast in the
// t-loop -> no scalar-cache / L2 latency inside the scan. e_n computed by independent
// exp2 per n (no serial e*=E chain, no ladder_check / dual code path).
__global__ __launch_bounds__(64) void k3_scanA(
    const unsigned* __restrict__ xdbl, const bf* __restrict__ u_ws,
    const float* __restrict__ A_log, const float* __restrict__ dt_proj_w,
    const float* __restrict__ dt_proj_b,
    float* __restrict__ hloc, float* __restrict__ ssum_ws) {
  int s = blockIdx.x >> 6, chunk = blockIdx.x & (NC - 1);
  int d = threadIdx.x;
  float A2[DSN];
#pragma unroll
  for (int n = 0; n < DSN; n++)
    A2[n] = -__expf(A_log[d * DSN + n]) * 1.44269504088896f;
  float w0 = dt_proj_w[2 * d], w1 = dt_proj_w[2 * d + 1], bd = dt_proj_b[d];
  float h[DSN];
#pragma unroll
  for (int n = 0; n < DSN; n++) h[n] = 0.f;
  float ss = 0.f;
  size_t base = (size_t)s * LL + (size_t)chunk * CL;
  const unsigned short* up = (const unsigned short*)u_ws + base * DI + d;
  const unsigned* xrow = xdbl + base * XROW;
  // per-lane row preload: lane d holds row t=d (dt + B = 9 dwords), coalesced one-shot load
  const unsigned* rr = xrow + d * XROW;
  unsigned pdt = rr[0];
  uint4 pB0 = *(const uint4*)(rr + 4);
  uint4 pB1 = *(const uint4*)(rr + 8);
#pragma unroll 4
  for (int t = 0; t < CL; t++) {
    unsigned sdt = RL(pdt, t);
    unsigned bw[8];
    bw[0] = RL(pB0.x, t); bw[1] = RL(pB0.y, t); bw[2] = RL(pB0.z, t); bw[3] = RL(pB0.w, t);
    bw[4] = RL(pB1.x, t); bw[5] = RL(pB1.y, t); bw[6] = RL(pB1.z, t); bw[7] = RL(pB1.w, t);
    float x = fmaf(bhi(sdt), w1, fmaf(blo(sdt), w0, bd));
    float delta = softplus_fast(x);
    float uu = us2f(up[(size_t)t * DI]);
    float du = delta * uu;
    ss += delta;
#pragma unroll
    for (int n = 0; n < DSN; n++) {
      float e = EXP2F(delta * A2[n]);
      float Bn = (n & 1) ? bhi(bw[n >> 1]) : blo(bw[n >> 1]);
      h[n] = fmaf(h[n], e, du * Bn);
    }
  }
  size_t ob = (size_t)blockIdx.x * (DSN * DI) + d;
#pragma unroll
  for (int n = 0; n < DSN; n++) hloc[ob + n * DI] = h[n];
  ssum_ws[blockIdx.x * DI + d] = ss;
}

// ---------------- K4: cross-chunk combine; Aprod recomputed from ssum; hin overwrites hloc ----------------
// (unchanged)
__global__ __launch_bounds__(64) void k4_combine(
    const float* __restrict__ ssum_ws, const float* __restrict__ A_log, float* hloc_hin) {
  int s = blockIdx.x, d = threadIdx.x;
  float A2[DSN];
#pragma unroll
  for (int n = 0; n < DSN; n++)
    A2[n] = -__expf(A_log[d * DSN + n]) * 1.44269504088896f;
  float h[DSN];
#pragma unroll
  for (int n = 0; n < DSN; n++) h[n] = 0.f;
  for (int k = 0; k < NC; k++) {
    size_t base = (size_t)(s * NC + k) * (DSN * DI) + d;
    float ss = ssum_ws[(s * NC + k) * DI + d];
#pragma unroll
    for (int n = 0; n < DSN; n++) {
      float ap = EXP2F(A2[n] * ss);
      float hl = hloc_hin[base + n * DI];
      hloc_hin[base + n * DI] = h[n];
      h[n] = fmaf(h[n], ap, hl);
    }
  }
}

// ---------------- K56: scan pass C (y2 -> LDS) + z-gate + out_proj + residual -> output (fp32) ----------------
// grid: BB*NC = 1024 blocks (b, chunk), 256 threads; LDS = y2S only (33792 B -> 4 blocks/CU).
// NEW scan phase: per-lane row preload of this wave's xdbl chunk (17 dw/lane, coalesced
// one-shot vector load) + v_readlane broadcast per t -> the 64-step loop has no scalar-load
// latency; B/C land in SGPRs so unpack stays SALU and FMAs take them as SGPR operands.
// e_n = exp2(delta*A2[n]) per n: independent (trans pipe co-issues), no serial e*=E chain.
__global__ __launch_bounds__(256, 4) void k56_scan_final(
    const unsigned* __restrict__ xdbl, const bf* __restrict__ u_ws,
    const float* __restrict__ A_log, const float* __restrict__ dt_proj_w,
    const float* __restrict__ dt_proj_b, const float* __restrict__ Dw,
    const float* __restrict__ hin, const bf* __restrict__ xn_ws,
    const float* __restrict__ in_proj_w, const float* __restrict__ out_proj_w,
    float* __restrict__ out) {
  __shared__ unsigned y2S[4 * 64 * 33];            // per-g: 64 rows(t) x 33 dw (d-pairs)
  int b = blockIdx.x >> 6;
  int chunk = blockIdx.x & (NC - 1);
  int l0 = chunk * CL;
  int tid = threadIdx.x;
  int g = tid >> 6, d = tid & 63;
  // wave-uniform sequence index, forced into an SGPR
  int s_u = __builtin_amdgcn_readfirstlane(g * BB + b);
  float A2[DSN];
#pragma unroll
  for (int n = 0; n < DSN; n++)
    A2[n] = -__expf(A_log[d * DSN + n]) * 1.44269504088896f;
  float w0 = dt_proj_w[2 * d], w1 = dt_proj_w[2 * d + 1], bd = dt_proj_b[d];
  float Dd = Dw[d];
  float h[DSN];
  size_t hb = (size_t)(s_u * NC + chunk) * (DSN * DI) + d;
#pragma unroll
  for (int n = 0; n < DSN; n++) h[n] = hin[hb + n * DI];
  size_t base = (size_t)s_u * LL + (size_t)chunk * CL;
  const unsigned short* up = (const unsigned short*)u_ws + base * DI + d;
  const unsigned* xrow = xdbl + base * XROW;
  unsigned short* yout = (unsigned short*)y2S + g * 4224 + d;
  // per-lane row preload: lane d holds row t=d (17 dwords: dt + B + C)
  const unsigned* rr = xrow + d * XROW;
  unsigned pdt = rr[0];
  uint4 pB0 = *(const uint4*)(rr + 4);
  uint4 pB1 = *(const uint4*)(rr + 8);
  uint4 pC0 = *(const uint4*)(rr + 12);
  uint4 pC1 = *(const uint4*)(rr + 16);
#pragma unroll 4
  for (int t = 0; t < CL; t++) {
    unsigned sdt = RL(pdt, t);
    unsigned bw[8], cw[8];
    bw[0] = RL(pB0.x, t); bw[1] = RL(pB0.y, t); bw[2] = RL(pB0.z, t); bw[3] = RL(pB0.w, t);
    bw[4] = RL(pB1.x, t); bw[5] = RL(pB1.y, t); bw[6] = RL(pB1.z, t); bw[7] = RL(pB1.w, t);
    cw[0] = RL(pC0.x, t); cw[1] = RL(pC0.y, t); cw[2] = RL(pC0.z, t); cw[3] = RL(pC0.w, t);
    cw[4] = RL(pC1.x, t); cw[5] = RL(pC1.y, t); cw[6] = RL(pC1.z, t); cw[7] = RL(pC1.w, t);
    float x = fmaf(bhi(sdt), w1, fmaf(blo(sdt), w0, bd));
    float delta = softplus_fast(x);
    float uu = us2f(up[(size_t)t * DI]);
    float du = delta * uu;
    float y = 0.f;
#pragma unroll
    for (int n = 0; n < DSN; n++) {
      float e = EXP2F(delta * A2[n]);
      float Bn = (n & 1) ? bhi(bw[n >> 1]) : blo(bw[n >> 1]);
      float Cn = (n & 1) ? bhi(cw[n >> 1]) : blo(cw[n >> 1]);
      h[n] = fmaf(h[n], e, du * Bn);
      y = fmaf(h[n], Cn, y);
    }
    bf rv = f2bf(y + uu * Dd);
    yout[t * 66] = *(unsigned short*)&rv;
  }
  __syncthreads();
  // ---- gate + out_proj + residual (thread = (g, column j)); xn read from global, coalesced ----
  int j = d;
  const unsigned short* xnp = (const unsigned short*)xn_ws
                            + ((size_t)(b * CC + g * DM)) * LL + l0 + j;
  float acc[DI];
#pragma unroll
  for (int dd = 0; dd < DI; dd++) acc[dd] = 0.f;
#pragma unroll
  for (int c4 = 0; c4 < 4; c4++) {                 // z projection, r-chunked: acc64 + xc8 live
    float xc[8];
#pragma unroll
    for (int r8 = 0; r8 < 8; r8++)
      xc[r8] = us2f(xnp[(size_t)(c4 * 8 + r8) * LL]);   // lanes j consecutive -> coalesced 128B
#pragma unroll
    for (int dd = 0; dd < DI; dd++) {              // weights wave-uniform -> s_load
      const float* w = in_proj_w + (DI + dd) * DM + c4 * 8;
      float a = acc[dd];
#pragma unroll
      for (int r8 = 0; r8 < 8; r8++) a = fmaf(xc[r8], w[r8], a);
      acc[dd] = a;
    }
  }
  const unsigned* yrow = y2S + g * 2112 + j * 33;  // banks (j+k)%32 -> conflict-free
#pragma unroll
  for (int k = 0; k < 32; k++) {                   // gate: y3 = y2 * silu(z)
    unsigned v = yrow[k];
    float z0 = acc[2 * k], z1 = acc[2 * k + 1];
    acc[2 * k]     = blo(v) * (z0 * sigmoidf_(z0));
    acc[2 * k + 1] = bhi(v) * (z1 * sigmoidf_(z1));
  }
  float* ob = out + ((size_t)(b * CC + g * DM)) * LL + l0 + j;
  for (int jj = 0; jj < DM; jj++) {                // out_proj + residual (residual read coalesced)
    const float* w = out_proj_w + jj * DI;
    float a = us2f(xnp[(size_t)jj * LL]);
#pragma unroll
    for (int dd = 0; dd < DI; dd++) a = fmaf(acc[dd], w[dd], a);
    ob[(size_t)jj * LL] = a;                       // coalesced 256B
  }
}

extern "C" void kernel_launch(void* const* d_in, const int* in_sizes, int n_in,
                              void* d_out, int out_size, void* d_ws, size_t ws_size,
                              hipStream_t stream) {
  const float* input     = (const float*)d_in[0];
  const float* ln_g      = (const float*)d_in[1];
  const float* ln_b      = (const float*)d_in[2];
  const float* in_proj_w = (const float*)d_in[3];
  const float* conv_w    = (const float*)d_in[4];
  const float* conv_b    = (const float*)d_in[5];
  const float* x_proj_w  = (const float*)d_in[6];
  const float* dt_proj_w = (const float*)d_in[7];
  const float* dt_proj_b = (const float*)d_in[8];
  const float* A_log     = (const float*)d_in[9];
  const float* Dw        = (const float*)d_in[10];
  const float* out_proj_w= (const float*)d_in[11];
  float* out = (float*)d_out;

  char* ws = (char*)d_ws;
  bf*       u_ws  = (bf*)(ws);                    // 32 MiB
  unsigned* xdbl  = (unsigned*)(ws + 33554432);   // 20 MiB
  bf*       xn_ws = (bf*)(ws + 54525952);         // 16 MiB
  float*    hloc  = (float*)(ws + 71303168);      // 16 MiB (hin aliases after k4)
  float*    ssum  = (float*)(ws + 88080384);      // 1 MiB
  (void)in_sizes; (void)n_in; (void)out_size; (void)ws_size;

  hipLaunchKernelGGL(k1_ln_conv, dim3(BB * NT), dim3(256), 0, stream,
                     input, ln_g, ln_b, in_proj_w, conv_w, conv_b, u_ws, xn_ws);
  hipLaunchKernelGGL(k2_xproj, dim3(1024), dim3(256), 0, stream,
                     u_ws, x_proj_w, xdbl);
  hipLaunchKernelGGL(k3_scanA, dim3(GG * NC), dim3(64), 0, stream,
                     xdbl, u_ws, A_log, dt_proj_w, dt_proj_b, hloc, ssum);
  hipLaunchKernelGGL(k4_combine, dim3(GG), dim3(64), 0, stream,
                     ssum, A_log, hloc);
  hipLaunchKernelGGL(k56_scan_final, dim3(BB * NC), dim3(256), 0, stream,
                     xdbl, u_ws, A_log, dt_proj_w, dt_proj_b, Dw, hloc, xn_ws,
                     in_proj_w, out_proj_w, out);
}